// Round 1
// baseline (443.802 us; speedup 1.0000x reference)
//
#include <hip/hip_runtime.h>
#include <math.h>

#define Bc   16
#define HIDc 2048
#define Hc   32
#define Dc   64
#define KVc  4096
#define QKVO 6144        // 3*H*D
#define SCALEc 0.125f    // D^-0.5

// ---------------- Kernel 1: qkv[b][o] = sum_h x[b][h] * w_qkv[o][h] ----------------
// thread-per-output; 16 consecutive lanes share one w row (same-address broadcast),
// read 16 different x rows (L1-resident, x = 128 KB total).
__global__ __launch_bounds__(256) void qkv_kernel(const float* __restrict__ x,
                                                  const float* __restrict__ w,
                                                  float* __restrict__ qkv) {
    int g = blockIdx.x * 256 + threadIdx.x;   // g < 16*6144
    int b = g & 15;
    int o = g >> 4;
    const float4* xr = reinterpret_cast<const float4*>(x + (size_t)b * HIDc);
    const float4* wr = reinterpret_cast<const float4*>(w + (size_t)o * HIDc);
    float acc = 0.f;
#pragma unroll 8
    for (int i = 0; i < HIDc / 4; ++i) {
        float4 a = xr[i];
        float4 c = wr[i];
        acc += a.x * c.x + a.y * c.y + a.z * c.z + a.w * c.w;
    }
    qkv[(size_t)b * QKVO + o] = acc;
}

// ---------------- Kernel 2: fused attention, one block per (b,h) ----------------
// 512 threads = 8 waves. Lane groups of 16 cover D=64 via float4 (cg = lane&15),
// 4 row-subgroups per wave (sg = lane>>4). Coalesced 16B/lane K/V loads.
__global__ __launch_bounds__(512) void attn_kernel(const float* __restrict__ qkv,
                                                   const float* __restrict__ bias,
                                                   const float* __restrict__ past_kv,
                                                   float* __restrict__ attn_out) {
    __shared__ float sc[KVc];        // scores -> exp values (16 KB)
    __shared__ float red[16];        // 8 wave maxes + 8 wave sums
    __shared__ float accs[8 * 64];   // per-wave partial outputs

    int blk  = blockIdx.x;
    int b    = blk >> 5;
    int h    = blk & 31;
    int t    = threadIdx.x;
    int lane = t & 63;
    int wid  = t >> 6;
    int sg   = lane >> 4;
    int cg   = lane & 15;

    const float* qp   = qkv + (size_t)b * QKVO + h * Dc;                 // t=0 slice
    const float* knew = qkv + (size_t)b * QKVO + HIDc + h * Dc;          // t=1 slice
    const float* vnew = qkv + (size_t)b * QKVO + 2 * HIDc + h * Dc;      // t=2 slice
    const size_t kvstride = (size_t)KVc * Dc;
    const float* pastK = past_kv + (size_t)(b * Hc + h) * kvstride;
    const float* pastV = past_kv + (size_t)Bc * Hc * kvstride + (size_t)(b * Hc + h) * kvstride;
    const float* brow  = bias + (size_t)(b * Hc + h) * KVc;

    float4 q4 = reinterpret_cast<const float4*>(qp)[cg];

    int rbase = wid * 4 + sg;   // 8 waves * 4 subgroups = 32 rows per step

    // ---- QK^T ----
    for (int it = 0; it < KVc / 32; it += 4) {
        float4 k4[4];
#pragma unroll
        for (int u = 0; u < 4; ++u) {
            int r = (it + u) * 32 + rbase;
            const float* kr = (r == KVc - 1) ? knew : (pastK + (size_t)r * Dc);
            k4[u] = reinterpret_cast<const float4*>(kr)[cg];
        }
#pragma unroll
        for (int u = 0; u < 4; ++u) {
            int r = (it + u) * 32 + rbase;
            float p = q4.x * k4[u].x + q4.y * k4[u].y + q4.z * k4[u].z + q4.w * k4[u].w;
            p += __shfl_xor(p, 1);
            p += __shfl_xor(p, 2);
            p += __shfl_xor(p, 4);
            p += __shfl_xor(p, 8);
            if (cg == 0) sc[r] = fmaf(p, SCALEc, brow[r]);
        }
    }
    __syncthreads();

    // ---- softmax (unnormalized; fold 1/sum at the end) ----
    int c0 = t * 8;   // 512 threads * 8 = 4096
    float m = -1e30f;
#pragma unroll
    for (int i = 0; i < 8; ++i) m = fmaxf(m, sc[c0 + i]);
#pragma unroll
    for (int off = 32; off >= 1; off >>= 1) m = fmaxf(m, __shfl_xor(m, off));
    if (lane == 0) red[wid] = m;
    __syncthreads();
    float M = red[0];
#pragma unroll
    for (int i = 1; i < 8; ++i) M = fmaxf(M, red[i]);

    float lsum = 0.f;
#pragma unroll
    for (int i = 0; i < 8; ++i) {
        float e = __expf(sc[c0 + i] - M);
        sc[c0 + i] = e;
        lsum += e;
    }
#pragma unroll
    for (int off = 32; off >= 1; off >>= 1) lsum += __shfl_xor(lsum, off);
    if (lane == 0) red[8 + wid] = lsum;
    __syncthreads();
    float ssum = 0.f;
#pragma unroll
    for (int i = 0; i < 8; ++i) ssum += red[8 + i];
    float inv = 1.0f / ssum;

    // ---- PV ----
    float a0 = 0.f, a1 = 0.f, a2 = 0.f, a3 = 0.f;
    for (int it = 0; it < KVc / 32; it += 4) {
        float4 v4[4];
        float  pw[4];
#pragma unroll
        for (int u = 0; u < 4; ++u) {
            int r = (it + u) * 32 + rbase;
            const float* vr = (r == KVc - 1) ? vnew : (pastV + (size_t)r * Dc);
            v4[u] = reinterpret_cast<const float4*>(vr)[cg];
            pw[u] = sc[r];
        }
#pragma unroll
        for (int u = 0; u < 4; ++u) {
            a0 = fmaf(pw[u], v4[u].x, a0);
            a1 = fmaf(pw[u], v4[u].y, a1);
            a2 = fmaf(pw[u], v4[u].z, a2);
            a3 = fmaf(pw[u], v4[u].w, a3);
        }
    }
    // reduce across the 4 row-subgroups within the wave
    a0 += __shfl_xor(a0, 16); a0 += __shfl_xor(a0, 32);
    a1 += __shfl_xor(a1, 16); a1 += __shfl_xor(a1, 32);
    a2 += __shfl_xor(a2, 16); a2 += __shfl_xor(a2, 32);
    a3 += __shfl_xor(a3, 16); a3 += __shfl_xor(a3, 32);
    if (lane < 16) {
        accs[wid * 64 + lane * 4 + 0] = a0;
        accs[wid * 64 + lane * 4 + 1] = a1;
        accs[wid * 64 + lane * 4 + 2] = a2;
        accs[wid * 64 + lane * 4 + 3] = a3;
    }
    __syncthreads();
    if (t < 64) {
        float s = 0.f;
#pragma unroll
        for (int w = 0; w < 8; ++w) s += accs[w * 64 + t];
        attn_out[(size_t)b * HIDc + h * Dc + t] = s * inv;
    }
}

// ---------------- Kernel 3: out[b][f] = sum_c attn[b][c] * w_o[f][c] ----------------
__global__ __launch_bounds__(256) void outproj_kernel(const float* __restrict__ attn,
                                                      const float* __restrict__ w_o,
                                                      float* __restrict__ out) {
    int g = blockIdx.x * 256 + threadIdx.x;   // g < 16*2048
    int b = g & 15;
    int f = g >> 4;
    const float4* ar = reinterpret_cast<const float4*>(attn + (size_t)b * HIDc);
    const float4* wr = reinterpret_cast<const float4*>(w_o + (size_t)f * HIDc);
    float acc = 0.f;
#pragma unroll 8
    for (int i = 0; i < HIDc / 4; ++i) {
        float4 a = ar[i];
        float4 c = wr[i];
        acc += a.x * c.x + a.y * c.y + a.z * c.z + a.w * c.w;
    }
    out[(size_t)b * HIDc + f] = acc;
}

extern "C" void kernel_launch(void* const* d_in, const int* in_sizes, int n_in,
                              void* d_out, int out_size, void* d_ws, size_t ws_size,
                              hipStream_t stream) {
    const float* x       = (const float*)d_in[0];
    const float* bias    = (const float*)d_in[1];
    const float* past_kv = (const float*)d_in[2];
    const float* w_qkv   = (const float*)d_in[3];
    const float* w_o     = (const float*)d_in[4];
    float* out = (float*)d_out;

    float* qkv  = (float*)d_ws;               // 16*6144 floats
    float* attn = qkv + (size_t)Bc * QKVO;    // 16*2048 floats

    qkv_kernel<<<dim3((Bc * QKVO) / 256), dim3(256), 0, stream>>>(x, w_qkv, qkv);
    attn_kernel<<<dim3(Bc * Hc), dim3(512), 0, stream>>>(qkv, bias, past_kv, attn);
    outproj_kernel<<<dim3((Bc * HIDc) / 256), dim3(256), 0, stream>>>(attn, w_o, out);
}

// Round 2
// 431.634 us; speedup vs baseline: 1.0282x; 1.0282x over previous
//
#include <hip/hip_runtime.h>
#include <math.h>

#define Bc     16
#define HIDc   2048
#define Hc     32
#define Dc     64
#define KVc    4096
#define QKVO   6144        // 3*H*D
#define SCALEc 0.125f      // D^-0.5
#define CHUNKS 4
#define CHUNK  1024        // KVc / CHUNKS

// ---------------- Kernel 1: qkv[b][o] = sum_h x[b][h] * w_qkv[o][h] ----------------
__global__ __launch_bounds__(256) void qkv_kernel(const float* __restrict__ x,
                                                  const float* __restrict__ w,
                                                  float* __restrict__ qkv) {
    int g = blockIdx.x * 256 + threadIdx.x;   // g < 16*6144
    int b = g & 15;
    int o = g >> 4;
    const float4* xr = reinterpret_cast<const float4*>(x + (size_t)b * HIDc);
    const float4* wr = reinterpret_cast<const float4*>(w + (size_t)o * HIDc);
    float acc = 0.f;
#pragma unroll 16
    for (int i = 0; i < HIDc / 4; ++i) {
        float4 a = xr[i];
        float4 c = wr[i];
        acc += a.x * c.x + a.y * c.y + a.z * c.z + a.w * c.w;
    }
    qkv[(size_t)b * QKVO + o] = acc;
}

// ---------------- Kernel 2a: chunked attention (flash-decoding) ----------------
// grid = B*H*CHUNKS = 2048 blocks, 256 threads (4 waves) -> 8 blocks/CU, 32 waves/CU.
// Each block: 1024 KV rows of one (b,h). Emits unnormalized partial O, local max, local sum.
__global__ __launch_bounds__(256) void attn_chunk_kernel(const float* __restrict__ qkv,
                                                         const float* __restrict__ bias,
                                                         const float* __restrict__ past_kv,
                                                         float* __restrict__ part_o,
                                                         float* __restrict__ part_ms) {
    __shared__ float sc[CHUNK];      // 4 KB
    __shared__ float red[8];
    __shared__ float accs[4 * 64];   // 1 KB

    int blk = blockIdx.x;
    int c   = blk & (CHUNKS - 1);
    int bh  = blk >> 2;              // b*32 + h
    int h   = bh & 31;
    int b   = bh >> 5;
    int t    = threadIdx.x;
    int lane = t & 63;
    int wid  = t >> 6;
    int sg   = lane >> 4;
    int cg   = lane & 15;
    int row0 = c * CHUNK;

    const float* qp   = qkv + (size_t)b * QKVO + h * Dc;
    const float* knew = qkv + (size_t)b * QKVO + HIDc + h * Dc;
    const float* vnew = qkv + (size_t)b * QKVO + 2 * HIDc + h * Dc;
    const size_t kvstride = (size_t)KVc * Dc;
    const float* pastK = past_kv + (size_t)bh * kvstride;
    const float* pastV = past_kv + (size_t)Bc * Hc * kvstride + (size_t)bh * kvstride;
    const float* brow  = bias + (size_t)bh * KVc;

    float4 q4 = reinterpret_cast<const float4*>(qp)[cg];
    int rbase = wid * 4 + sg;        // 4 waves * 4 subgroups = 16 rows per step

    // ---- QK^T for this chunk ----
    for (int it = 0; it < CHUNK / 16; it += 4) {
        float4 k4[4];
#pragma unroll
        for (int u = 0; u < 4; ++u) {
            int rl = (it + u) * 16 + rbase;
            int r  = row0 + rl;
            const float* kr = (r == KVc - 1) ? knew : (pastK + (size_t)r * Dc);
            k4[u] = reinterpret_cast<const float4*>(kr)[cg];
        }
#pragma unroll
        for (int u = 0; u < 4; ++u) {
            int rl = (it + u) * 16 + rbase;
            float p = q4.x * k4[u].x + q4.y * k4[u].y + q4.z * k4[u].z + q4.w * k4[u].w;
            p += __shfl_xor(p, 1);
            p += __shfl_xor(p, 2);
            p += __shfl_xor(p, 4);
            p += __shfl_xor(p, 8);
            if (cg == 0) sc[rl] = fmaf(p, SCALEc, brow[row0 + rl]);
        }
    }
    __syncthreads();

    // ---- local softmax (unnormalized; partials carry local max) ----
    int c0 = t * 4;                  // 256 threads * 4 = 1024
    float m = -1e30f;
#pragma unroll
    for (int i = 0; i < 4; ++i) m = fmaxf(m, sc[c0 + i]);
#pragma unroll
    for (int off = 32; off >= 1; off >>= 1) m = fmaxf(m, __shfl_xor(m, off));
    if (lane == 0) red[wid] = m;
    __syncthreads();
    float M = fmaxf(fmaxf(red[0], red[1]), fmaxf(red[2], red[3]));

    float lsum = 0.f;
#pragma unroll
    for (int i = 0; i < 4; ++i) {
        float e = __expf(sc[c0 + i] - M);
        sc[c0 + i] = e;
        lsum += e;
    }
#pragma unroll
    for (int off = 32; off >= 1; off >>= 1) lsum += __shfl_xor(lsum, off);
    if (lane == 0) red[4 + wid] = lsum;
    __syncthreads();
    float S = red[4] + red[5] + red[6] + red[7];

    // ---- PV for this chunk ----
    float a0 = 0.f, a1 = 0.f, a2 = 0.f, a3 = 0.f;
    for (int it = 0; it < CHUNK / 16; it += 4) {
        float4 v4[4];
        float  pw[4];
#pragma unroll
        for (int u = 0; u < 4; ++u) {
            int rl = (it + u) * 16 + rbase;
            int r  = row0 + rl;
            const float* vr = (r == KVc - 1) ? vnew : (pastV + (size_t)r * Dc);
            v4[u] = reinterpret_cast<const float4*>(vr)[cg];
            pw[u] = sc[rl];
        }
#pragma unroll
        for (int u = 0; u < 4; ++u) {
            a0 = fmaf(pw[u], v4[u].x, a0);
            a1 = fmaf(pw[u], v4[u].y, a1);
            a2 = fmaf(pw[u], v4[u].z, a2);
            a3 = fmaf(pw[u], v4[u].w, a3);
        }
    }
    a0 += __shfl_xor(a0, 16); a0 += __shfl_xor(a0, 32);
    a1 += __shfl_xor(a1, 16); a1 += __shfl_xor(a1, 32);
    a2 += __shfl_xor(a2, 16); a2 += __shfl_xor(a2, 32);
    a3 += __shfl_xor(a3, 16); a3 += __shfl_xor(a3, 32);
    if (lane < 16) {
        accs[wid * 64 + lane * 4 + 0] = a0;
        accs[wid * 64 + lane * 4 + 1] = a1;
        accs[wid * 64 + lane * 4 + 2] = a2;
        accs[wid * 64 + lane * 4 + 3] = a3;
    }
    __syncthreads();
    if (t < 64) {
        float s = 0.f;
#pragma unroll
        for (int w = 0; w < 4; ++w) s += accs[w * 64 + t];
        part_o[((size_t)bh * CHUNKS + c) * Dc + t] = s;   // unnormalized, local-max ref
    }
    if (t == 0) {
        part_ms[((size_t)bh * CHUNKS + c) * 2 + 0] = M;
        part_ms[((size_t)bh * CHUNKS + c) * 2 + 1] = S;
    }
}

// ---------------- Kernel 2b: combine chunk partials ----------------
__global__ __launch_bounds__(64) void attn_combine_kernel(const float* __restrict__ part_o,
                                                          const float* __restrict__ part_ms,
                                                          float* __restrict__ attn_out) {
    int bh = blockIdx.x;             // b*32 + h
    int d  = threadIdx.x;
    float mc[CHUNKS], sc_[CHUNKS];
#pragma unroll
    for (int c = 0; c < CHUNKS; ++c) {
        mc[c]  = part_ms[((size_t)bh * CHUNKS + c) * 2 + 0];
        sc_[c] = part_ms[((size_t)bh * CHUNKS + c) * 2 + 1];
    }
    float M = mc[0];
#pragma unroll
    for (int c = 1; c < CHUNKS; ++c) M = fmaxf(M, mc[c]);
    float S = 0.f, o = 0.f;
#pragma unroll
    for (int c = 0; c < CHUNKS; ++c) {
        float w = __expf(mc[c] - M);
        S += w * sc_[c];
        o += w * part_o[((size_t)bh * CHUNKS + c) * Dc + d];
    }
    attn_out[(size_t)bh * Dc + d] = o / S;
}

// ---------------- Kernel 3: out[b][f] = sum_c attn[b][c] * w_o[f][c] ----------------
__global__ __launch_bounds__(256) void outproj_kernel(const float* __restrict__ attn,
                                                      const float* __restrict__ w_o,
                                                      float* __restrict__ out) {
    int g = blockIdx.x * 256 + threadIdx.x;   // g < 16*2048
    int b = g & 15;
    int f = g >> 4;
    const float4* ar = reinterpret_cast<const float4*>(attn + (size_t)b * HIDc);
    const float4* wr = reinterpret_cast<const float4*>(w_o + (size_t)f * HIDc);
    float acc = 0.f;
#pragma unroll 16
    for (int i = 0; i < HIDc / 4; ++i) {
        float4 a = ar[i];
        float4 c = wr[i];
        acc += a.x * c.x + a.y * c.y + a.z * c.z + a.w * c.w;
    }
    out[(size_t)b * HIDc + f] = acc;
}

extern "C" void kernel_launch(void* const* d_in, const int* in_sizes, int n_in,
                              void* d_out, int out_size, void* d_ws, size_t ws_size,
                              hipStream_t stream) {
    const float* x       = (const float*)d_in[0];
    const float* bias    = (const float*)d_in[1];
    const float* past_kv = (const float*)d_in[2];
    const float* w_qkv   = (const float*)d_in[3];
    const float* w_o     = (const float*)d_in[4];
    float* out = (float*)d_out;

    float* qkv     = (float*)d_ws;                          // 16*6144
    float* attn    = qkv + (size_t)Bc * QKVO;               // 16*2048
    float* part_o  = attn + (size_t)Bc * HIDc;              // 16*32*4*64
    float* part_ms = part_o + (size_t)Bc * Hc * CHUNKS * Dc; // 16*32*4*2

    qkv_kernel<<<dim3((Bc * QKVO) / 256), dim3(256), 0, stream>>>(x, w_qkv, qkv);
    attn_chunk_kernel<<<dim3(Bc * Hc * CHUNKS), dim3(256), 0, stream>>>(qkv, bias, past_kv, part_o, part_ms);
    attn_combine_kernel<<<dim3(Bc * Hc), dim3(64), 0, stream>>>(part_o, part_ms, attn);
    outproj_kernel<<<dim3((Bc * HIDc) / 256), dim3(256), 0, stream>>>(attn, w_o, out);
}

// Round 3
// 295.060 us; speedup vs baseline: 1.5041x; 1.4629x over previous
//
#include <hip/hip_runtime.h>
#include <math.h>

#define Bc     16
#define HIDc   2048
#define Hc     32
#define Dc     64
#define KVc    4096
#define QKVO   6144        // 3*H*D
#define SCALEc 0.125f      // D^-0.5
#define CHUNKS 4
#define CHUNK  1024        // KVc / CHUNKS

// ---------------- Kernel 1: qkv[b][o] = sum_h x[b][h] * w_qkv[o][h] ----------------
// Block owns (b, 64 outputs). x row (8 KB) staged in LDS; each wave streams 16 w rows
// with fully-coalesced 64-lane float4 loads (1 KB/instr), shfl-reduce the dot.
__global__ __launch_bounds__(256) void qkv_kernel(const float* __restrict__ x,
                                                  const float* __restrict__ w,
                                                  float* __restrict__ qkv) {
    __shared__ float4 xs[512];   // 8 KB
    int blk = blockIdx.x;        // 16 b * 96 ogroups = 1536
    int b   = blk & 15;
    int og  = blk >> 4;
    int t = threadIdx.x, lane = t & 63, wid = t >> 6;
    const float4* xr = reinterpret_cast<const float4*>(x + (size_t)b * HIDc);
    xs[t]       = xr[t];
    xs[t + 256] = xr[t + 256];
    __syncthreads();
    int o0 = og * 64 + wid * 16;
#pragma unroll 2
    for (int i = 0; i < 16; ++i) {
        int o = o0 + i;
        const float4* wr = reinterpret_cast<const float4*>(w + (size_t)o * HIDc);
        float acc = 0.f;
#pragma unroll
        for (int j = 0; j < 8; ++j) {
            float4 a = xs[lane + 64 * j];
            float4 c = wr[lane + 64 * j];
            acc += a.x * c.x + a.y * c.y + a.z * c.z + a.w * c.w;
        }
#pragma unroll
        for (int off = 32; off >= 1; off >>= 1) acc += __shfl_xor(acc, off);
        if (lane == 0) qkv[(size_t)b * QKVO + o] = acc;
    }
}

// ---------------- Kernel 2a: chunked attention (flash-decoding) — UNCHANGED ----------------
__global__ __launch_bounds__(256) void attn_chunk_kernel(const float* __restrict__ qkv,
                                                         const float* __restrict__ bias,
                                                         const float* __restrict__ past_kv,
                                                         float* __restrict__ part_o,
                                                         float* __restrict__ part_ms) {
    __shared__ float sc[CHUNK];      // 4 KB
    __shared__ float red[8];
    __shared__ float accs[4 * 64];   // 1 KB

    int blk = blockIdx.x;
    int c   = blk & (CHUNKS - 1);
    int bh  = blk >> 2;              // b*32 + h
    int h   = bh & 31;
    int b   = bh >> 5;
    int t    = threadIdx.x;
    int lane = t & 63;
    int wid  = t >> 6;
    int sg   = lane >> 4;
    int cg   = lane & 15;
    int row0 = c * CHUNK;

    const float* qp   = qkv + (size_t)b * QKVO + h * Dc;
    const float* knew = qkv + (size_t)b * QKVO + HIDc + h * Dc;
    const float* vnew = qkv + (size_t)b * QKVO + 2 * HIDc + h * Dc;
    const size_t kvstride = (size_t)KVc * Dc;
    const float* pastK = past_kv + (size_t)bh * kvstride;
    const float* pastV = past_kv + (size_t)Bc * Hc * kvstride + (size_t)bh * kvstride;
    const float* brow  = bias + (size_t)bh * KVc;

    float4 q4 = reinterpret_cast<const float4*>(qp)[cg];
    int rbase = wid * 4 + sg;        // 4 waves * 4 subgroups = 16 rows per step

    for (int it = 0; it < CHUNK / 16; it += 4) {
        float4 k4[4];
#pragma unroll
        for (int u = 0; u < 4; ++u) {
            int rl = (it + u) * 16 + rbase;
            int r  = row0 + rl;
            const float* kr = (r == KVc - 1) ? knew : (pastK + (size_t)r * Dc);
            k4[u] = reinterpret_cast<const float4*>(kr)[cg];
        }
#pragma unroll
        for (int u = 0; u < 4; ++u) {
            int rl = (it + u) * 16 + rbase;
            float p = q4.x * k4[u].x + q4.y * k4[u].y + q4.z * k4[u].z + q4.w * k4[u].w;
            p += __shfl_xor(p, 1);
            p += __shfl_xor(p, 2);
            p += __shfl_xor(p, 4);
            p += __shfl_xor(p, 8);
            if (cg == 0) sc[rl] = fmaf(p, SCALEc, brow[row0 + rl]);
        }
    }
    __syncthreads();

    int c0 = t * 4;                  // 256 threads * 4 = 1024
    float m = -1e30f;
#pragma unroll
    for (int i = 0; i < 4; ++i) m = fmaxf(m, sc[c0 + i]);
#pragma unroll
    for (int off = 32; off >= 1; off >>= 1) m = fmaxf(m, __shfl_xor(m, off));
    if (lane == 0) red[wid] = m;
    __syncthreads();
    float M = fmaxf(fmaxf(red[0], red[1]), fmaxf(red[2], red[3]));

    float lsum = 0.f;
#pragma unroll
    for (int i = 0; i < 4; ++i) {
        float e = __expf(sc[c0 + i] - M);
        sc[c0 + i] = e;
        lsum += e;
    }
#pragma unroll
    for (int off = 32; off >= 1; off >>= 1) lsum += __shfl_xor(lsum, off);
    if (lane == 0) red[4 + wid] = lsum;
    __syncthreads();
    float S = red[4] + red[5] + red[6] + red[7];

    float a0 = 0.f, a1 = 0.f, a2 = 0.f, a3 = 0.f;
    for (int it = 0; it < CHUNK / 16; it += 4) {
        float4 v4[4];
        float  pw[4];
#pragma unroll
        for (int u = 0; u < 4; ++u) {
            int rl = (it + u) * 16 + rbase;
            int r  = row0 + rl;
            const float* vr = (r == KVc - 1) ? vnew : (pastV + (size_t)r * Dc);
            v4[u] = reinterpret_cast<const float4*>(vr)[cg];
            pw[u] = sc[rl];
        }
#pragma unroll
        for (int u = 0; u < 4; ++u) {
            a0 = fmaf(pw[u], v4[u].x, a0);
            a1 = fmaf(pw[u], v4[u].y, a1);
            a2 = fmaf(pw[u], v4[u].z, a2);
            a3 = fmaf(pw[u], v4[u].w, a3);
        }
    }
    a0 += __shfl_xor(a0, 16); a0 += __shfl_xor(a0, 32);
    a1 += __shfl_xor(a1, 16); a1 += __shfl_xor(a1, 32);
    a2 += __shfl_xor(a2, 16); a2 += __shfl_xor(a2, 32);
    a3 += __shfl_xor(a3, 16); a3 += __shfl_xor(a3, 32);
    if (lane < 16) {
        accs[wid * 64 + lane * 4 + 0] = a0;
        accs[wid * 64 + lane * 4 + 1] = a1;
        accs[wid * 64 + lane * 4 + 2] = a2;
        accs[wid * 64 + lane * 4 + 3] = a3;
    }
    __syncthreads();
    if (t < 64) {
        float s = 0.f;
#pragma unroll
        for (int w = 0; w < 4; ++w) s += accs[w * 64 + t];
        part_o[((size_t)bh * CHUNKS + c) * Dc + t] = s;
    }
    if (t == 0) {
        part_ms[((size_t)bh * CHUNKS + c) * 2 + 0] = M;
        part_ms[((size_t)bh * CHUNKS + c) * 2 + 1] = S;
    }
}

// ---------------- Kernel 2b: combine chunk partials ----------------
__global__ __launch_bounds__(64) void attn_combine_kernel(const float* __restrict__ part_o,
                                                          const float* __restrict__ part_ms,
                                                          float* __restrict__ attn_out) {
    int bh = blockIdx.x;
    int d  = threadIdx.x;
    float mc[CHUNKS], sc_[CHUNKS];
#pragma unroll
    for (int c = 0; c < CHUNKS; ++c) {
        mc[c]  = part_ms[((size_t)bh * CHUNKS + c) * 2 + 0];
        sc_[c] = part_ms[((size_t)bh * CHUNKS + c) * 2 + 1];
    }
    float M = mc[0];
#pragma unroll
    for (int c = 1; c < CHUNKS; ++c) M = fmaxf(M, mc[c]);
    float S = 0.f, o = 0.f;
#pragma unroll
    for (int c = 0; c < CHUNKS; ++c) {
        float w = __expf(mc[c] - M);
        S += w * sc_[c];
        o += w * part_o[((size_t)bh * CHUNKS + c) * Dc + d];
    }
    attn_out[(size_t)bh * Dc + d] = o / S;
}

// ---------------- Kernel 3: out[b][f] = sum_c attn[b][c] * w_o[f][c] ----------------
// Same wave-per-row structure as kernel 1.
__global__ __launch_bounds__(256) void outproj_kernel(const float* __restrict__ attn,
                                                      const float* __restrict__ w_o,
                                                      float* __restrict__ out) {
    __shared__ float4 as[512];   // 8 KB
    int blk = blockIdx.x;        // 16 b * 32 fgroups = 512
    int b   = blk & 15;
    int fg  = blk >> 4;
    int t = threadIdx.x, lane = t & 63, wid = t >> 6;
    const float4* ar = reinterpret_cast<const float4*>(attn + (size_t)b * HIDc);
    as[t]       = ar[t];
    as[t + 256] = ar[t + 256];
    __syncthreads();
    int f0 = fg * 64 + wid * 16;
#pragma unroll 2
    for (int i = 0; i < 16; ++i) {
        int f = f0 + i;
        const float4* wr = reinterpret_cast<const float4*>(w_o + (size_t)f * HIDc);
        float acc = 0.f;
#pragma unroll
        for (int j = 0; j < 8; ++j) {
            float4 a = as[lane + 64 * j];
            float4 c = wr[lane + 64 * j];
            acc += a.x * c.x + a.y * c.y + a.z * c.z + a.w * c.w;
        }
#pragma unroll
        for (int off = 32; off >= 1; off >>= 1) acc += __shfl_xor(acc, off);
        if (lane == 0) out[(size_t)b * HIDc + f] = acc;
    }
}

extern "C" void kernel_launch(void* const* d_in, const int* in_sizes, int n_in,
                              void* d_out, int out_size, void* d_ws, size_t ws_size,
                              hipStream_t stream) {
    const float* x       = (const float*)d_in[0];
    const float* bias    = (const float*)d_in[1];
    const float* past_kv = (const float*)d_in[2];
    const float* w_qkv   = (const float*)d_in[3];
    const float* w_o     = (const float*)d_in[4];
    float* out = (float*)d_out;

    float* qkv     = (float*)d_ws;                           // 16*6144
    float* attn    = qkv + (size_t)Bc * QKVO;                // 16*2048
    float* part_o  = attn + (size_t)Bc * HIDc;               // 16*32*4*64
    float* part_ms = part_o + (size_t)Bc * Hc * CHUNKS * Dc; // 16*32*4*2

    qkv_kernel<<<dim3(Bc * (QKVO / 64)), dim3(256), 0, stream>>>(x, w_qkv, qkv);
    attn_chunk_kernel<<<dim3(Bc * Hc * CHUNKS), dim3(256), 0, stream>>>(qkv, bias, past_kv, part_o, part_ms);
    attn_combine_kernel<<<dim3(Bc * Hc), dim3(64), 0, stream>>>(part_o, part_ms, attn);
    outproj_kernel<<<dim3(Bc * (HIDc / 64)), dim3(256), 0, stream>>>(attn, w_o, out);
}

// Round 4
// 273.958 us; speedup vs baseline: 1.6200x; 1.0770x over previous
//
#include <hip/hip_runtime.h>
#include <math.h>

#define Bc     16
#define HIDc   2048
#define Hc     32
#define Dc     64
#define KVc    4096
#define QKVO   6144        // 3*H*D
#define SCALEc 0.125f      // D^-0.5
#define CHUNKS 4
#define CHUNK  1024        // KVc / CHUNKS

// ---------------- Kernel 1: qkv[b][o] = sum_h x[b][h] * w_qkv[o][h] ----------------
__global__ __launch_bounds__(256) void qkv_kernel(const float* __restrict__ x,
                                                  const float* __restrict__ w,
                                                  float* __restrict__ qkv) {
    __shared__ float4 xs[512];   // 8 KB
    int blk = blockIdx.x;        // 16 b * 96 ogroups = 1536
    int b   = blk & 15;
    int og  = blk >> 4;
    int t = threadIdx.x, lane = t & 63, wid = t >> 6;
    const float4* xr = reinterpret_cast<const float4*>(x + (size_t)b * HIDc);
    xs[t]       = xr[t];
    xs[t + 256] = xr[t + 256];
    __syncthreads();
    int o0 = og * 64 + wid * 16;
#pragma unroll 2
    for (int i = 0; i < 16; ++i) {
        int o = o0 + i;
        const float4* wr = reinterpret_cast<const float4*>(w + (size_t)o * HIDc);
        float acc = 0.f;
#pragma unroll
        for (int j = 0; j < 8; ++j) {
            float4 a = xs[lane + 64 * j];
            float4 c = wr[lane + 64 * j];
            acc += a.x * c.x + a.y * c.y + a.z * c.z + a.w * c.w;
        }
#pragma unroll
        for (int off = 32; off >= 1; off >>= 1) acc += __shfl_xor(acc, off);
        if (lane == 0) qkv[(size_t)b * QKVO + o] = acc;
    }
}

// online-softmax update for one row's probability p and V fragment v
__device__ __forceinline__ void online_upd(float p, const float4& v,
                                           float& m, float& s, float4& acc) {
    float mn  = fmaxf(m, p);
    float sc_ = __expf(m - mn);
    float e   = __expf(p - mn);
    s = fmaf(s, sc_, e);
    acc.x = fmaf(acc.x, sc_, e * v.x);
    acc.y = fmaf(acc.y, sc_, e * v.y);
    acc.z = fmaf(acc.z, sc_, e * v.z);
    acc.w = fmaf(acc.w, sc_, e * v.w);
    m = mn;
}

// ---------------- Kernel 2a: one-pass chunked attention (flash-decoding) ----------------
// grid = B*H*CHUNKS = 2048 blocks, 256 threads -> 8 blocks/CU target.
// Single K+V sweep with online softmax per 16-lane subgroup; 8 loads in flight/wave.
__global__ __launch_bounds__(256, 8) void attn_chunk_kernel(const float* __restrict__ qkv,
                                                            const float* __restrict__ bias,
                                                            const float* __restrict__ past_kv,
                                                            float* __restrict__ part_o,
                                                            float* __restrict__ part_ms) {
    __shared__ float bs[CHUNK];       // bias slice, 4 KB
    __shared__ float accs[16][65];    // subgroup partial O (padded)
    __shared__ float pm[16], ps[16];

    int blk = blockIdx.x;
    int c   = blk & (CHUNKS - 1);
    int bh  = blk >> 2;               // b*32 + h
    int h   = bh & 31;
    int b   = bh >> 5;
    int t    = threadIdx.x;
    int lane = t & 63;
    int wid  = t >> 6;
    int sg   = lane >> 4;
    int cg   = lane & 15;
    int row0 = c * CHUNK;

    // stage bias chunk into LDS (coalesced float4)
    reinterpret_cast<float4*>(bs)[t] =
        reinterpret_cast<const float4*>(bias + (size_t)bh * KVc + row0)[t];

    const float* qp = qkv + (size_t)b * QKVO + h * Dc;
    float4 q4 = reinterpret_cast<const float4*>(qp)[cg];

    const size_t kvstride = (size_t)KVc * Dc;
    const float* pastK = past_kv + (size_t)bh * kvstride + (size_t)row0 * Dc;
    const float* pastV = past_kv + (size_t)(Bc * Hc) * kvstride + (size_t)bh * kvstride
                         + (size_t)row0 * Dc;

    __syncthreads();

    int rbase = wid * 4 + sg;         // 16 subgroups cover 16 consecutive rows
    float m = -1e30f, s = 0.f;
    float4 acc = {0.f, 0.f, 0.f, 0.f};

    int nclean = (c == CHUNKS - 1) ? 15 : 16;   // peel last 64 rows of last chunk
    for (int ot = 0; ot < nclean; ++ot) {
        int it = ot * 4;
        float4 k4[4], v4[4];
#pragma unroll
        for (int u = 0; u < 4; ++u) {
            int rl = (it + u) * 16 + rbase;
            k4[u] = reinterpret_cast<const float4*>(pastK + (size_t)rl * Dc)[cg];
        }
#pragma unroll
        for (int u = 0; u < 4; ++u) {
            int rl = (it + u) * 16 + rbase;
            v4[u] = reinterpret_cast<const float4*>(pastV + (size_t)rl * Dc)[cg];
        }
#pragma unroll
        for (int u = 0; u < 4; ++u) {
            int rl = (it + u) * 16 + rbase;
            float p = q4.x * k4[u].x + q4.y * k4[u].y + q4.z * k4[u].z + q4.w * k4[u].w;
            p += __shfl_xor(p, 1);
            p += __shfl_xor(p, 2);
            p += __shfl_xor(p, 4);
            p += __shfl_xor(p, 8);
            p = fmaf(p, SCALEc, bs[rl]);
            online_upd(p, v4[u], m, s, acc);
        }
    }
    if (c == CHUNKS - 1) {
        // rows 960..1023 of the chunk; local row CHUNK-1 is the new K/V token
        const float* knew = qkv + (size_t)b * QKVO + HIDc + h * Dc;
        const float* vnew = qkv + (size_t)b * QKVO + 2 * HIDc + h * Dc;
        int it = 60;
        float4 k4[4], v4[4];
#pragma unroll
        for (int u = 0; u < 4; ++u) {
            int rl = (it + u) * 16 + rbase;
            const float* kr = (rl == CHUNK - 1) ? knew : (pastK + (size_t)rl * Dc);
            k4[u] = reinterpret_cast<const float4*>(kr)[cg];
        }
#pragma unroll
        for (int u = 0; u < 4; ++u) {
            int rl = (it + u) * 16 + rbase;
            const float* vr = (rl == CHUNK - 1) ? vnew : (pastV + (size_t)rl * Dc);
            v4[u] = reinterpret_cast<const float4*>(vr)[cg];
        }
#pragma unroll
        for (int u = 0; u < 4; ++u) {
            int rl = (it + u) * 16 + rbase;
            float p = q4.x * k4[u].x + q4.y * k4[u].y + q4.z * k4[u].z + q4.w * k4[u].w;
            p += __shfl_xor(p, 1);
            p += __shfl_xor(p, 2);
            p += __shfl_xor(p, 4);
            p += __shfl_xor(p, 8);
            p = fmaf(p, SCALEc, bs[rl]);
            online_upd(p, v4[u], m, s, acc);
        }
    }

    // merge 16 subgroup partials within the block
    int sgid = wid * 4 + sg;
    if (cg == 0) { pm[sgid] = m; ps[sgid] = s; }
    accs[sgid][cg * 4 + 0] = acc.x;
    accs[sgid][cg * 4 + 1] = acc.y;
    accs[sgid][cg * 4 + 2] = acc.z;
    accs[sgid][cg * 4 + 3] = acc.w;
    __syncthreads();
    if (t < 64) {
        float M = pm[0];
#pragma unroll
        for (int i = 1; i < 16; ++i) M = fmaxf(M, pm[i]);
        float S = 0.f, o = 0.f;
#pragma unroll
        for (int i = 0; i < 16; ++i) {
            float w = __expf(pm[i] - M);
            S += w * ps[i];
            o += w * accs[i][t];
        }
        part_o[((size_t)bh * CHUNKS + c) * Dc + t] = o;
        if (t == 0) {
            part_ms[((size_t)bh * CHUNKS + c) * 2 + 0] = M;
            part_ms[((size_t)bh * CHUNKS + c) * 2 + 1] = S;
        }
    }
}

// ---------------- Kernel 2b: combine chunk partials ----------------
__global__ __launch_bounds__(64) void attn_combine_kernel(const float* __restrict__ part_o,
                                                          const float* __restrict__ part_ms,
                                                          float* __restrict__ attn_out) {
    int bh = blockIdx.x;
    int d  = threadIdx.x;
    float mc[CHUNKS], sc_[CHUNKS];
#pragma unroll
    for (int c = 0; c < CHUNKS; ++c) {
        mc[c]  = part_ms[((size_t)bh * CHUNKS + c) * 2 + 0];
        sc_[c] = part_ms[((size_t)bh * CHUNKS + c) * 2 + 1];
    }
    float M = mc[0];
#pragma unroll
    for (int c = 1; c < CHUNKS; ++c) M = fmaxf(M, mc[c]);
    float S = 0.f, o = 0.f;
#pragma unroll
    for (int c = 0; c < CHUNKS; ++c) {
        float w = __expf(mc[c] - M);
        S += w * sc_[c];
        o += w * part_o[((size_t)bh * CHUNKS + c) * Dc + d];
    }
    attn_out[(size_t)bh * Dc + d] = o / S;
}

// ---------------- Kernel 3: out[b][f] = sum_c attn[b][c] * w_o[f][c] ----------------
__global__ __launch_bounds__(256) void outproj_kernel(const float* __restrict__ attn,
                                                      const float* __restrict__ w_o,
                                                      float* __restrict__ out) {
    __shared__ float4 as[512];   // 8 KB
    int blk = blockIdx.x;        // 16 b * 32 fgroups = 512
    int b   = blk & 15;
    int fg  = blk >> 4;
    int t = threadIdx.x, lane = t & 63, wid = t >> 6;
    const float4* ar = reinterpret_cast<const float4*>(attn + (size_t)b * HIDc);
    as[t]       = ar[t];
    as[t + 256] = ar[t + 256];
    __syncthreads();
    int f0 = fg * 64 + wid * 16;
#pragma unroll 2
    for (int i = 0; i < 16; ++i) {
        int f = f0 + i;
        const float4* wr = reinterpret_cast<const float4*>(w_o + (size_t)f * HIDc);
        float acc = 0.f;
#pragma unroll
        for (int j = 0; j < 8; ++j) {
            float4 a = as[lane + 64 * j];
            float4 c = wr[lane + 64 * j];
            acc += a.x * c.x + a.y * c.y + a.z * c.z + a.w * c.w;
        }
#pragma unroll
        for (int off = 32; off >= 1; off >>= 1) acc += __shfl_xor(acc, off);
        if (lane == 0) out[(size_t)b * HIDc + f] = acc;
    }
}

extern "C" void kernel_launch(void* const* d_in, const int* in_sizes, int n_in,
                              void* d_out, int out_size, void* d_ws, size_t ws_size,
                              hipStream_t stream) {
    const float* x       = (const float*)d_in[0];
    const float* bias    = (const float*)d_in[1];
    const float* past_kv = (const float*)d_in[2];
    const float* w_qkv   = (const float*)d_in[3];
    const float* w_o     = (const float*)d_in[4];
    float* out = (float*)d_out;

    float* qkv     = (float*)d_ws;                           // 16*6144
    float* attn    = qkv + (size_t)Bc * QKVO;                // 16*2048
    float* part_o  = attn + (size_t)Bc * HIDc;               // 16*32*4*64
    float* part_ms = part_o + (size_t)Bc * Hc * CHUNKS * Dc; // 16*32*4*2

    qkv_kernel<<<dim3(Bc * (QKVO / 64)), dim3(256), 0, stream>>>(x, w_qkv, qkv);
    attn_chunk_kernel<<<dim3(Bc * Hc * CHUNKS), dim3(256), 0, stream>>>(qkv, bias, past_kv, part_o, part_ms);
    attn_combine_kernel<<<dim3(Bc * Hc), dim3(64), 0, stream>>>(part_o, part_ms, attn);
    outproj_kernel<<<dim3(Bc * (HIDc / 64)), dim3(256), 0, stream>>>(attn, w_o, out);
}